// Round 3
// baseline (4446.644 us; speedup 1.0000x reference)
//
#include <hip/hip_runtime.h>
#include <hip/hip_bf16.h>

typedef __hip_bfloat16 bf16;

__device__ __forceinline__ float b2f(bf16 x){ return __bfloat162float(x); }
__device__ __forceinline__ bf16  f2b(float x){ return __float2bfloat16(x); }
__device__ __forceinline__ float ldA(const float* p){ return *p; }
__device__ __forceinline__ float ldA(const bf16* p){ return b2f(*p); }

#define BTOK 2048
#define CC 1024
#define AA 1024
#define IDIM 3584
#define NEXP 8

// ---------------- reductions ----------------
__device__ __forceinline__ float block_sum256(float v, float* red){
  #pragma unroll
  for (int o = 32; o > 0; o >>= 1) v += __shfl_down(v, o, 64);
  int lane = threadIdx.x & 63, wid = threadIdx.x >> 6;
  if (lane == 0) red[wid] = v;
  __syncthreads();
  float s = red[0] + red[1] + red[2] + red[3];
  __syncthreads();
  return s;
}

// ---------------- fused pre_ln + ln1 (f32 in, f32 out) ----------------
__global__ __launch_bounds__(256) void k_ln_pre(
    const float* __restrict__ hidden,
    const float* __restrict__ g0, const float* __restrict__ b0,
    const float* __restrict__ g1, const float* __restrict__ b1,
    float* __restrict__ xout, float* __restrict__ hout){
  __shared__ float red[8];
  int t = blockIdx.x, tid = threadIdx.x;
  const float* src = hidden + (size_t)t * CC;
  float v[4];
  #pragma unroll
  for (int i = 0; i < 4; ++i) v[i] = src[tid + 256*i];
  float mean = block_sum256(v[0]+v[1]+v[2]+v[3], red) * (1.f/CC);
  float vs = 0.f;
  #pragma unroll
  for (int i = 0; i < 4; ++i){ float d = v[i]-mean; vs += d*d; }
  float var = block_sum256(vs, red) * (1.f/CC);
  float inv = rsqrtf(var + 1e-5f);
  float xv[4];
  #pragma unroll
  for (int i = 0; i < 4; ++i){
    int c = tid + 256*i;
    xv[i] = (v[i]-mean)*inv*g0[c] + b0[c];
    xout[(size_t)t*CC + c] = xv[i];
  }
  float mean2 = block_sum256(xv[0]+xv[1]+xv[2]+xv[3], red) * (1.f/CC);
  vs = 0.f;
  #pragma unroll
  for (int i = 0; i < 4; ++i){ float d = xv[i]-mean2; vs += d*d; }
  float var2 = block_sum256(vs, red) * (1.f/CC);
  float inv2 = rsqrtf(var2 + 1e-5f);
  #pragma unroll
  for (int i = 0; i < 4; ++i){
    int c = tid + 256*i;
    hout[(size_t)t*CC + c] = (xv[i]-mean2)*inv2*g1[c] + b1[c];
  }
}

// ---------------- token-shift + maa mix -> z_{w,k,v,r,g} (bf16 scratch) ----------------
__global__ __launch_bounds__(256) void k_mix_att(
    const float* __restrict__ h,
    const float* __restrict__ maa_x, const float* __restrict__ w1, const float* __restrict__ w2,
    const float* __restrict__ maa_w, const float* __restrict__ maa_k, const float* __restrict__ maa_v,
    const float* __restrict__ maa_r, const float* __restrict__ maa_g,
    bf16* __restrict__ zw, bf16* __restrict__ zk, bf16* __restrict__ zv,
    bf16* __restrict__ zr, bf16* __restrict__ zg){
  int t = blockIdx.x, tid = threadIdx.x;
  int tb = t & 1023;  // position within batch (T=1024)
  __shared__ float hs[CC], xxs[CC], xxxs[CC], t160[160];
  #pragma unroll
  for (int i = 0; i < 4; ++i){
    int c = tid + 256*i;
    float hv = h[(size_t)t*CC + c];
    float pv = tb ? h[(size_t)(t-1)*CC + c] : 0.f;  // time_shift: zero-pad first token
    float xx = pv - hv;
    hs[c] = hv; xxs[c] = xx;
    xxxs[c] = hv + xx * maa_x[c];
  }
  __syncthreads();
  if (tid < 160){
    float acc = 0.f;
    for (int c = 0; c < CC; ++c) acc = fmaf(xxxs[c], w1[c*160 + tid], acc);
    t160[tid] = tanhf(acc);
  }
  __syncthreads();
  const float* maas[5] = {maa_w, maa_k, maa_v, maa_r, maa_g};
  bf16* zs[5] = {zw, zk, zv, zr, zg};
  #pragma unroll
  for (int f = 0; f < 5; ++f){
    #pragma unroll
    for (int i = 0; i < 4; ++i){
      int c = tid + 256*i;
      float acc = 0.f;
      #pragma unroll
      for (int d = 0; d < 32; ++d)
        acc = fmaf(t160[f*32 + d], w2[(size_t)(f*32 + d)*CC + c], acc);
      float z = hs[c] + xxs[c] * (maas[f][c] + acc);
      zs[f][(size_t)t*CC + c] = f2b(z);
    }
  }
}

// ---------------- generic tiled GEMM: O = A[M,K] @ W[N,K]^T (W is f32) ----------------
// epi 0: Of32[oi] = acc (+ addsrc)      epi 1: Obf[oi] = bf16(relu(acc)^2)
#define BM 64
#define BN 64
#define BK 16
template <typename TA>
__global__ __launch_bounds__(256) void k_gemm(
    const TA* __restrict__ A, const float* __restrict__ W,
    float* __restrict__ Of32, bf16* __restrict__ Obf,
    int M, int N, int K, const float* __restrict__ addsrc, int epi){
  __shared__ float As[BK][BM+1];
  __shared__ float Bs[BK][BN+1];
  int bn = blockIdx.x * BN, bm = blockIdx.y * BM;
  int tid = threadIdx.x;
  int tx = tid & 15, ty = tid >> 4;
  int lr = tid >> 2;          // 0..63
  int lk = (tid & 3) * 4;     // 0,4,8,12
  const TA*    Ap = A + (size_t)(bm + lr)*K + lk;
  const float* Wp = W + (size_t)(bn + lr)*K + lk;
  float acc[4][4] = {};
  for (int k0 = 0; k0 < K; k0 += BK){
    #pragma unroll
    for (int j = 0; j < 4; ++j){
      As[lk+j][lr] = ldA(Ap + k0 + j);
      Bs[lk+j][lr] = Wp[k0 + j];
    }
    __syncthreads();
    #pragma unroll
    for (int kk = 0; kk < BK; ++kk){
      float av[4], bv[4];
      #pragma unroll
      for (int i = 0; i < 4; ++i) av[i] = As[kk][ty*4 + i];
      #pragma unroll
      for (int j = 0; j < 4; ++j) bv[j] = Bs[kk][tx*4 + j];
      #pragma unroll
      for (int i = 0; i < 4; ++i)
        #pragma unroll
        for (int j = 0; j < 4; ++j) acc[i][j] = fmaf(av[i], bv[j], acc[i][j]);
    }
    __syncthreads();
  }
  #pragma unroll
  for (int i = 0; i < 4; ++i){
    int row = bm + ty*4 + i;
    #pragma unroll
    for (int j = 0; j < 4; ++j){
      int col = bn + tx*4 + j;
      size_t oi = (size_t)row*N + col;
      float v = acc[i][j];
      if (epi == 0){
        if (addsrc) v += addsrc[oi];
        Of32[oi] = v;
      } else {
        v = v > 0.f ? v : 0.f;
        Obf[oi] = f2b(v*v);
      }
    }
  }
}

// ---------------- MoE gather/scatter GEMM (A bf16, W f32) ----------------
// mode 0 (key): in row = rowmap[gpos], out row = gpos (dense), store relu(acc)^2 bf16
// mode 1 (val): in row = gpos,          out row = rowmap[gpos], f32 +=
__global__ __launch_bounds__(256) void k_gemm_moe(
    const bf16* __restrict__ A, const float* __restrict__ Wbase, size_t wstride,
    float* __restrict__ Of32, bf16* __restrict__ Obf, int N, int K,
    const int* __restrict__ rowmap, const int* __restrict__ counts,
    const int* __restrict__ offsets, int mode){
  int e = blockIdx.z;
  int cnt = counts[e];
  int mbase = blockIdx.y * BM;
  if (mbase >= cnt) return;
  int obase = offsets[e];
  const float* W = Wbase + (size_t)e * wstride;
  __shared__ float As[BK][BM+1];
  __shared__ float Bs[BK][BN+1];
  int bn = blockIdx.x * BN;
  int tid = threadIdx.x;
  int tx = tid & 15, ty = tid >> 4;
  int lr = tid >> 2;
  int lk = (tid & 3) * 4;
  int lrow_ld = mbase + lr;
  int gpos_ld = obase + (lrow_ld < cnt ? lrow_ld : 0);
  gpos_ld = gpos_ld < 0 ? 0 : (gpos_ld > BTOK-1 ? BTOK-1 : gpos_ld);
  int arow = (mode == 0) ? rowmap[gpos_ld] : gpos_ld;
  arow = arow < 0 ? 0 : (arow > BTOK-1 ? BTOK-1 : arow);  // safety clamp
  const bf16*  Ap = A + (size_t)arow*K + lk;
  const float* Wp = W + (size_t)(bn + lr)*K + lk;
  float acc[4][4] = {};
  for (int k0 = 0; k0 < K; k0 += BK){
    #pragma unroll
    for (int j = 0; j < 4; ++j){
      As[lk+j][lr] = b2f(Ap[k0 + j]);
      Bs[lk+j][lr] = Wp[k0 + j];
    }
    __syncthreads();
    #pragma unroll
    for (int kk = 0; kk < BK; ++kk){
      float av[4], bv[4];
      #pragma unroll
      for (int i = 0; i < 4; ++i) av[i] = As[kk][ty*4 + i];
      #pragma unroll
      for (int j = 0; j < 4; ++j) bv[j] = Bs[kk][tx*4 + j];
      #pragma unroll
      for (int i = 0; i < 4; ++i)
        #pragma unroll
        for (int j = 0; j < 4; ++j) acc[i][j] = fmaf(av[i], bv[j], acc[i][j]);
    }
    __syncthreads();
  }
  #pragma unroll
  for (int i = 0; i < 4; ++i){
    int lrow = mbase + ty*4 + i;
    if (lrow >= cnt) continue;
    int gpos = obase + lrow;
    int orow = (mode == 0) ? gpos : rowmap[gpos];
    orow = orow < 0 ? 0 : (orow > BTOK-1 ? BTOK-1 : orow);
    #pragma unroll
    for (int j = 0; j < 4; ++j){
      int col = bn + tx*4 + j;
      size_t oi = (size_t)orow*N + col;
      if (mode == 0){
        float v = acc[i][j] > 0.f ? acc[i][j] : 0.f;
        Obf[oi] = f2b(v*v);
      } else {
        Of32[oi] += acc[i][j];   // unique (row,col) writer across experts
      }
    }
  }
}

// ---------------- WKV scan: one block per (b,h), 64 threads (column m per lane) ----------------
// ob may alias tdb: each element is read before being overwritten by the same thread.
__global__ __launch_bounds__(64) void k_wkv(
    const float* __restrict__ rb, const float* __restrict__ kb,
    const float* __restrict__ vb, const float* __restrict__ tdb,
    const float* __restrict__ tdbias, const float* __restrict__ u,
    float* __restrict__ ob){
  int b = blockIdx.x >> 4, hh = blockIdx.x & 15;
  int lane = threadIdx.x;
  __shared__ float rs[64], ks[64], ws[64], us[64];
  us[lane] = u[hh*64 + lane];
  float bias = tdbias[hh*64 + lane];
  float s[64];
  #pragma unroll
  for (int n = 0; n < 64; ++n) s[n] = 0.f;
  __syncthreads();
  for (int t = 0; t < 1024; ++t){
    size_t idx = ((size_t)(b*1024 + t))*AA + hh*64 + lane;
    float rt = rb[idx], kt = kb[idx], vt = vb[idx];
    float wt = expf(-expf(tdb[idx] + bias));
    rs[lane] = rt; ks[lane] = kt; ws[lane] = wt;
    __syncthreads();
    float out = 0.f;
    #pragma unroll
    for (int n = 0; n < 64; ++n){
      float kv = ks[n] * vt;                         // k[n]*v[m]
      out = fmaf(rs[n], fmaf(us[n], kv, s[n]), out); // r·(u∘kv + s_old)
      s[n] = fmaf(ws[n], s[n], kv);                  // s = kv + w[n]*s
    }
    ob[idx] = out;
    __syncthreads();
  }
}

// ---------------- group-norm over heads + silu(g) gate -> ao (f32) ----------------
__global__ __launch_bounds__(256) void k_gnorm_gate(
    const float* __restrict__ ob, const float* __restrict__ gb,
    const float* __restrict__ lg, const float* __restrict__ lb, float* __restrict__ ao){
  int t = blockIdx.x, tid = threadIdx.x;
  int lane = tid & 63, wid = tid >> 6;
  #pragma unroll
  for (int i = 0; i < 4; ++i){
    int head = wid*4 + i;
    int cidx = head*64 + lane;
    size_t idx = (size_t)t*AA + cidx;
    float v = ob[idx];
    float s1 = v, s2 = v*v;
    #pragma unroll
    for (int o = 32; o > 0; o >>= 1){
      s1 += __shfl_xor(s1, o, 64);
      s2 += __shfl_xor(s2, o, 64);
    }
    float m   = s1 * (1.f/64.f);
    float var = s2 * (1.f/64.f) - m*m;
    float nv  = (v - m) * rsqrtf(var + 6.4e-4f) * lg[cidx] + lb[cidx]; // eps=1e-5*64
    float gv  = gb[idx];
    float gate = gv / (1.f + expf(-gv));  // silu
    ao[idx] = nv * gate;
  }
}

// ---------------- ln2 + ffn token-shift mix -> zfr,zfk (bf16 scratch) ----------------
__global__ __launch_bounds__(256) void k_ln2mix(
    const float* __restrict__ x2,
    const float* __restrict__ g2, const float* __restrict__ b2v,
    const float* __restrict__ fmaa_r, const float* __restrict__ fmaa_k,
    bf16* __restrict__ zfr, bf16* __restrict__ zfk){
  __shared__ float red[8];
  int t = blockIdx.x, tid = threadIdx.x;
  int tb = t & 1023;
  float cur[4], prv[4];
  #pragma unroll
  for (int i = 0; i < 4; ++i){
    int c = tid + 256*i;
    cur[i] = x2[(size_t)t*CC + c];
    prv[i] = tb ? x2[(size_t)(t-1)*CC + c] : 0.f;
  }
  float m1 = block_sum256(cur[0]+cur[1]+cur[2]+cur[3], red) * (1.f/CC);
  float vs = 0.f;
  #pragma unroll
  for (int i = 0; i < 4; ++i){ float d = cur[i]-m1; vs += d*d; }
  float inv1 = rsqrtf(block_sum256(vs, red)*(1.f/CC) + 1e-5f);
  float m2 = block_sum256(prv[0]+prv[1]+prv[2]+prv[3], red) * (1.f/CC);
  vs = 0.f;
  #pragma unroll
  for (int i = 0; i < 4; ++i){ float d = prv[i]-m2; vs += d*d; }
  float inv2 = rsqrtf(block_sum256(vs, red)*(1.f/CC) + 1e-5f);
  #pragma unroll
  for (int i = 0; i < 4; ++i){
    int c = tid + 256*i;
    float hc = (cur[i]-m1)*inv1*g2[c] + b2v[c];
    float hp = tb ? ((prv[i]-m2)*inv2*g2[c] + b2v[c]) : 0.f;
    float d = hp - hc;
    zfr[(size_t)t*CC + c] = f2b(hc + d * fmaa_r[c]);
    zfk[(size_t)t*CC + c] = f2b(hc + d * fmaa_k[c]);
  }
}

// ---------------- expert routing ----------------
__global__ __launch_bounds__(256) void k_route(
    const int* __restrict__ ids, int* __restrict__ rowmap,
    int* __restrict__ counts, int* __restrict__ offsets){
  __shared__ int cnt[8], cur[8], off[8];
  int tid = threadIdx.x;
  if (tid < 8){ cnt[tid] = 0; cur[tid] = 0; }
  __syncthreads();
  for (int t = tid; t < BTOK; t += 256){
    int e = (ids[t] * 5099) & 7;
    atomicAdd(&cnt[e], 1);
  }
  __syncthreads();
  if (tid == 0){
    int acc = 0;
    for (int e = 0; e < 8; ++e){ off[e] = acc; offsets[e] = acc; counts[e] = cnt[e]; acc += cnt[e]; }
  }
  __syncthreads();
  for (int t = tid; t < BTOK; t += 256){
    int e = (ids[t] * 5099) & 7;
    int pos = off[e] + atomicAdd(&cur[e], 1);
    rowmap[pos] = t;
  }
}

// ---------------- small elementwise ----------------
__global__ void k_tanh_f(const float* __restrict__ in, float* __restrict__ out, int n){
  int i = blockIdx.x*256 + threadIdx.x;
  if (i >= n) return;
  out[i] = tanhf(in[i]);
}
__global__ void k_transpose_f(const float* __restrict__ in, float* __restrict__ out, int R, int Ccol){
  int idx = blockIdx.x*256 + threadIdx.x;
  if (idx >= R*Ccol) return;
  int r = idx / Ccol, c = idx % Ccol;
  out[c*R + r] = in[idx];
}
__global__ void k_final(const float* __restrict__ x2, const float* __restrict__ rr,
                        const float* __restrict__ val, float* __restrict__ out, int n){
  int i = blockIdx.x*256 + threadIdx.x;
  if (i >= n) return;
  float r = 1.f / (1.f + expf(-rr[i]));
  out[i] = x2[i] + r*val[i];
}

// ---------------- launch ----------------
extern "C" void kernel_launch(void* const* d_in, const int* in_sizes, int n_in,
                              void* d_out, int out_size, void* d_ws, size_t ws_size,
                              hipStream_t stream) {
  const float* hidden  = (const float*)d_in[0];
  const int*   ids     = (const int*)  d_in[1];
  const float* pre_g   = (const float*)d_in[2];
  const float* pre_b   = (const float*)d_in[3];
  const float* ln1_g   = (const float*)d_in[4];
  const float* ln1_b   = (const float*)d_in[5];
  const float* ln2_g   = (const float*)d_in[6];
  const float* ln2_b   = (const float*)d_in[7];
  const float* maa_x   = (const float*)d_in[8];
  const float* maa_w   = (const float*)d_in[9];
  const float* maa_k   = (const float*)d_in[10];
  const float* maa_v   = (const float*)d_in[11];
  const float* maa_r   = (const float*)d_in[12];
  const float* maa_g   = (const float*)d_in[13];
  const float* maa_w1  = (const float*)d_in[14];
  const float* maa_w2  = (const float*)d_in[15];
  const float* att_td  = (const float*)d_in[16];
  const float* td_w1   = (const float*)d_in[17];
  const float* td_w2   = (const float*)d_in[18];
  const float* att_u   = (const float*)d_in[19];
  const float* att_wr  = (const float*)d_in[20];
  const float* att_wk  = (const float*)d_in[21];
  const float* att_wv  = (const float*)d_in[22];
  const float* att_wg  = (const float*)d_in[23];
  const float* att_wo  = (const float*)d_in[24];
  const float* lnx_g   = (const float*)d_in[25];
  const float* lnx_b   = (const float*)d_in[26];
  const float* fmaa_k  = (const float*)d_in[27];
  const float* fmaa_r  = (const float*)d_in[28];
  const float* ffn_wr  = (const float*)d_in[29];
  const float* sh_wk   = (const float*)d_in[30];
  const float* sh_wv   = (const float*)d_in[31];
  const float* ex_wk   = (const float*)d_in[32];
  const float* ex_wv   = (const float*)d_in[33];
  (void)ws_size; (void)n_in; (void)in_sizes; (void)out_size;

  // ---- workspace layout, lifetime-aliased (total ≈ 69.6 MB) ----
  // F = 8 MiB (one [2048,1024] f32 plane)
  char* base = (char*)d_ws;
  const size_t F = (size_t)BTOK * CC * 4;
  float* x      = (float*)(base + 0*F);         // S1 -> S12; x2 aliases x (same-elem add in epi)
  float* x2     = x;
  float* h      = (float*)(base + 1*F);         // S1 -> S2
  float* rbuf   = h;                            // S3 -> S5
  float* kbuf   = (float*)(base + 2*F);         // S3 -> S5
  float* vbuf   = (float*)(base + 3*F);         // S3 -> S5
  bf16*  hk2    = (bf16*)(base + 2*F);          // 14 MB over kbuf+vbuf, S10 -> S11
  float* gbuf   = (float*)(base + 4*F);         // S3 -> S6
  float* val    = gbuf;                         // S10 -> S12
  float* tdbuf  = (float*)(base + 5*F);         // S4 -> S5
  float* wkvout = tdbuf;                        // S5 writes same idx after read -> S6
  float* recraw = tdbuf;                        // S9 -> S12 (wkvout dead after S6)
  bf16*  zw     = (bf16*)(base + 6*F);          // z region: [48,68) MB
  bf16*  zk     = zw + (size_t)BTOK*CC;
  bf16*  zv     = zk + (size_t)BTOK*CC;
  bf16*  zr     = zv + (size_t)BTOK*CC;
  bf16*  zg     = zr + (size_t)BTOK*CC;
  float* ao     = (float*)(base + 6*F);         // 8 MB over zw+zk (dead after S4/S3), S6 -> S7
  bf16*  zfr    = zv;                           // S8 -> S9 (zv dead after S3)
  bf16*  zfk    = zr;                           // S8 -> S11a (zr dead after S3)
  char*  misc   = base + 6*F + (size_t)5*BTOK*CC*2;   // 68 MB
  float* tmp64  = (float*)misc;                               // 512 KB
  float* tanh64 = (float*)(misc + (size_t)BTOK*64*4);         // 512 KB
  float* tdw1T  = (float*)(misc + (size_t)BTOK*64*8);         // 256 KB
  float* tdw2T  = tdw1T + (size_t)64*CC;                      // 256 KB
  int*   rowmap = (int*)(tdw2T + (size_t)AA*64);              // 8 KB
  int*   counts = rowmap + BTOK;
  int*   offsets= counts + 64;

  // 1. pre_ln + ln1
  k_ln_pre<<<BTOK, 256, 0, stream>>>(hidden, pre_g, pre_b, ln1_g, ln1_b, x, h);
  // 2. attention maa mix -> z_{w,k,v,r,g}
  k_mix_att<<<BTOK, 256, 0, stream>>>(h, maa_x, maa_w1, maa_w2,
                                      maa_w, maa_k, maa_v, maa_r, maa_g,
                                      zw, zk, zv, zr, zg);
  // 3. r,k,v,g projections
  dim3 g1024(CC/BN, BTOK/BM);
  k_gemm<bf16><<<g1024, 256, 0, stream>>>(zr, att_wr, rbuf, nullptr, BTOK, AA, CC, nullptr, 0);
  k_gemm<bf16><<<g1024, 256, 0, stream>>>(zk, att_wk, kbuf, nullptr, BTOK, AA, CC, nullptr, 0);
  k_gemm<bf16><<<g1024, 256, 0, stream>>>(zv, att_wv, vbuf, nullptr, BTOK, AA, CC, nullptr, 0);
  k_gemm<bf16><<<g1024, 256, 0, stream>>>(zg, att_wg, gbuf, nullptr, BTOK, AA, CC, nullptr, 0);
  // 4. td path
  k_transpose_f<<<(CC*64 + 255)/256, 256, 0, stream>>>(td_w1, tdw1T, CC, 64);
  k_transpose_f<<<(64*AA + 255)/256, 256, 0, stream>>>(td_w2, tdw2T, 64, AA);
  k_gemm<bf16><<<dim3(1, BTOK/BM), 256, 0, stream>>>(zw, tdw1T, tmp64, nullptr, BTOK, 64, CC, nullptr, 0);
  k_tanh_f<<<(BTOK*64 + 255)/256, 256, 0, stream>>>(tmp64, tanh64, BTOK*64);
  k_gemm<float><<<dim3(AA/BN, BTOK/BM), 256, 0, stream>>>(tanh64, tdw2T, tdbuf, nullptr, BTOK, AA, 64, nullptr, 0);
  // 5. WKV scan (td bias added inside; wkvout aliases tdbuf safely)
  k_wkv<<<32, 64, 0, stream>>>(rbuf, kbuf, vbuf, tdbuf, att_td, att_u, wkvout);
  // 6. group-norm + silu gate -> ao
  k_gnorm_gate<<<BTOK, 256, 0, stream>>>(wkvout, gbuf, lnx_g, lnx_b, ao);
  // 7. output proj + residual -> x2 (aliases x; element-wise read-then-write)
  k_gemm<float><<<g1024, 256, 0, stream>>>(ao, att_wo, x2, nullptr, BTOK, CC, AA, x, 0);
  // 8. ln2 + ffn mix
  k_ln2mix<<<BTOK, 256, 0, stream>>>(x2, ln2_g, ln2_b, fmaa_r, fmaa_k, zfr, zfk);
  // 9. receptance
  k_gemm<bf16><<<g1024, 256, 0, stream>>>(zfr, ffn_wr, recraw, nullptr, BTOK, CC, CC, nullptr, 0);
  // 10. shared expert (relu^2 fused into key GEMM epilogue)
  k_gemm<bf16><<<dim3(IDIM/BN, BTOK/BM), 256, 0, stream>>>(zfk, sh_wk, nullptr, hk2, BTOK, IDIM, CC, nullptr, 1);
  k_gemm<bf16><<<g1024, 256, 0, stream>>>(hk2, sh_wv, val, nullptr, BTOK, CC, IDIM, nullptr, 0);
  // 11. routed experts
  k_route<<<1, 256, 0, stream>>>(ids, rowmap, counts, offsets);
  k_gemm_moe<<<dim3(IDIM/BN, BTOK/BM, NEXP), 256, 0, stream>>>(
      zfk, ex_wk, (size_t)IDIM*CC, nullptr, hk2, IDIM, CC, rowmap, counts, offsets, 0);
  k_gemm_moe<<<dim3(CC/BN, BTOK/BM, NEXP), 256, 0, stream>>>(
      hk2, ex_wv, (size_t)CC*IDIM, val, nullptr, CC, IDIM, rowmap, counts, offsets, 1);
  // 12. final combine -> f32 out
  k_final<<<(BTOK*CC + 255)/256, 256, 0, stream>>>(x2, recraw, val, (float*)d_out, BTOK*CC);
}

// Round 4
// 2998.258 us; speedup vs baseline: 1.4831x; 1.4831x over previous
//
#include <hip/hip_runtime.h>
#include <hip/hip_bf16.h>

typedef __hip_bfloat16 bf16;

__device__ __forceinline__ float b2f(bf16 x){ return __bfloat162float(x); }
__device__ __forceinline__ bf16  f2b(float x){ return __float2bfloat16(x); }
__device__ __forceinline__ float ldA(const float* p){ return *p; }
__device__ __forceinline__ float ldA(const bf16* p){ return b2f(*p); }

#define BTOK 2048
#define CC 1024
#define AA 1024
#define IDIM 3584
#define NEXP 8
#define CHUNK 64
#define NCHUNK 16   // 1024 / CHUNK

// ---------------- reductions ----------------
__device__ __forceinline__ float block_sum256(float v, float* red){
  #pragma unroll
  for (int o = 32; o > 0; o >>= 1) v += __shfl_down(v, o, 64);
  int lane = threadIdx.x & 63, wid = threadIdx.x >> 6;
  if (lane == 0) red[wid] = v;
  __syncthreads();
  float s = red[0] + red[1] + red[2] + red[3];
  __syncthreads();
  return s;
}

// ---------------- fused pre_ln + ln1 (f32 in, f32 out) ----------------
__global__ __launch_bounds__(256) void k_ln_pre(
    const float* __restrict__ hidden,
    const float* __restrict__ g0, const float* __restrict__ b0,
    const float* __restrict__ g1, const float* __restrict__ b1,
    float* __restrict__ xout, float* __restrict__ hout){
  __shared__ float red[8];
  int t = blockIdx.x, tid = threadIdx.x;
  const float* src = hidden + (size_t)t * CC;
  float v[4];
  #pragma unroll
  for (int i = 0; i < 4; ++i) v[i] = src[tid + 256*i];
  float mean = block_sum256(v[0]+v[1]+v[2]+v[3], red) * (1.f/CC);
  float vs = 0.f;
  #pragma unroll
  for (int i = 0; i < 4; ++i){ float d = v[i]-mean; vs += d*d; }
  float var = block_sum256(vs, red) * (1.f/CC);
  float inv = rsqrtf(var + 1e-5f);
  float xv[4];
  #pragma unroll
  for (int i = 0; i < 4; ++i){
    int c = tid + 256*i;
    xv[i] = (v[i]-mean)*inv*g0[c] + b0[c];
    xout[(size_t)t*CC + c] = xv[i];
  }
  float mean2 = block_sum256(xv[0]+xv[1]+xv[2]+xv[3], red) * (1.f/CC);
  vs = 0.f;
  #pragma unroll
  for (int i = 0; i < 4; ++i){ float d = xv[i]-mean2; vs += d*d; }
  float var2 = block_sum256(vs, red) * (1.f/CC);
  float inv2 = rsqrtf(var2 + 1e-5f);
  #pragma unroll
  for (int i = 0; i < 4; ++i){
    int c = tid + 256*i;
    hout[(size_t)t*CC + c] = (xv[i]-mean2)*inv2*g1[c] + b1[c];
  }
}

// ---------------- token-shift + maa mix -> z_{w,k,v,r,g} (bf16 scratch) ----------------
__global__ __launch_bounds__(256) void k_mix_att(
    const float* __restrict__ h,
    const float* __restrict__ maa_x, const float* __restrict__ w1, const float* __restrict__ w2,
    const float* __restrict__ maa_w, const float* __restrict__ maa_k, const float* __restrict__ maa_v,
    const float* __restrict__ maa_r, const float* __restrict__ maa_g,
    bf16* __restrict__ zw, bf16* __restrict__ zk, bf16* __restrict__ zv,
    bf16* __restrict__ zr, bf16* __restrict__ zg){
  int t = blockIdx.x, tid = threadIdx.x;
  int tb = t & 1023;  // position within batch (T=1024)
  __shared__ float hs[CC], xxs[CC], xxxs[CC], t160[160];
  #pragma unroll
  for (int i = 0; i < 4; ++i){
    int c = tid + 256*i;
    float hv = h[(size_t)t*CC + c];
    float pv = tb ? h[(size_t)(t-1)*CC + c] : 0.f;  // time_shift: zero-pad first token
    float xx = pv - hv;
    hs[c] = hv; xxs[c] = xx;
    xxxs[c] = hv + xx * maa_x[c];
  }
  __syncthreads();
  if (tid < 160){
    float acc = 0.f;
    for (int c = 0; c < CC; ++c) acc = fmaf(xxxs[c], w1[c*160 + tid], acc);
    t160[tid] = tanhf(acc);
  }
  __syncthreads();
  const float* maas[5] = {maa_w, maa_k, maa_v, maa_r, maa_g};
  bf16* zs[5] = {zw, zk, zv, zr, zg};
  #pragma unroll
  for (int f = 0; f < 5; ++f){
    #pragma unroll
    for (int i = 0; i < 4; ++i){
      int c = tid + 256*i;
      float acc = 0.f;
      #pragma unroll
      for (int d = 0; d < 32; ++d)
        acc = fmaf(t160[f*32 + d], w2[(size_t)(f*32 + d)*CC + c], acc);
      float z = hs[c] + xxs[c] * (maas[f][c] + acc);
      zs[f][(size_t)t*CC + c] = f2b(z);
    }
  }
}

// ---------------- generic tiled GEMM: O = A[M,K] @ W[N,K]^T (W is f32) ----------------
// epi 0: Of32[oi] = acc (+ addsrc)      epi 1: Obf[oi] = bf16(relu(acc)^2)
#define BM 64
#define BN 64
#define BK 16
template <typename TA>
__global__ __launch_bounds__(256) void k_gemm(
    const TA* __restrict__ A, const float* __restrict__ W,
    float* __restrict__ Of32, bf16* __restrict__ Obf,
    int M, int N, int K, const float* __restrict__ addsrc, int epi){
  __shared__ float As[BK][BM+1];
  __shared__ float Bs[BK][BN+1];
  int bn = blockIdx.x * BN, bm = blockIdx.y * BM;
  int tid = threadIdx.x;
  int tx = tid & 15, ty = tid >> 4;
  int lr = tid >> 2;          // 0..63
  int lk = (tid & 3) * 4;     // 0,4,8,12
  const TA*    Ap = A + (size_t)(bm + lr)*K + lk;
  const float* Wp = W + (size_t)(bn + lr)*K + lk;
  float acc[4][4] = {};
  for (int k0 = 0; k0 < K; k0 += BK){
    #pragma unroll
    for (int j = 0; j < 4; ++j){
      As[lk+j][lr] = ldA(Ap + k0 + j);
      Bs[lk+j][lr] = Wp[k0 + j];
    }
    __syncthreads();
    #pragma unroll
    for (int kk = 0; kk < BK; ++kk){
      float av[4], bv[4];
      #pragma unroll
      for (int i = 0; i < 4; ++i) av[i] = As[kk][ty*4 + i];
      #pragma unroll
      for (int j = 0; j < 4; ++j) bv[j] = Bs[kk][tx*4 + j];
      #pragma unroll
      for (int i = 0; i < 4; ++i)
        #pragma unroll
        for (int j = 0; j < 4; ++j) acc[i][j] = fmaf(av[i], bv[j], acc[i][j]);
    }
    __syncthreads();
  }
  #pragma unroll
  for (int i = 0; i < 4; ++i){
    int row = bm + ty*4 + i;
    #pragma unroll
    for (int j = 0; j < 4; ++j){
      int col = bn + tx*4 + j;
      size_t oi = (size_t)row*N + col;
      float v = acc[i][j];
      if (epi == 0){
        if (addsrc) v += addsrc[oi];
        Of32[oi] = v;
      } else {
        v = v > 0.f ? v : 0.f;
        Obf[oi] = f2b(v*v);
      }
    }
  }
}

// ---------------- MoE gather/scatter GEMM (A bf16, W f32) ----------------
__global__ __launch_bounds__(256) void k_gemm_moe(
    const bf16* __restrict__ A, const float* __restrict__ Wbase, size_t wstride,
    float* __restrict__ Of32, bf16* __restrict__ Obf, int N, int K,
    const int* __restrict__ rowmap, const int* __restrict__ counts,
    const int* __restrict__ offsets, int mode){
  int e = blockIdx.z;
  int cnt = counts[e];
  int mbase = blockIdx.y * BM;
  if (mbase >= cnt) return;
  int obase = offsets[e];
  const float* W = Wbase + (size_t)e * wstride;
  __shared__ float As[BK][BM+1];
  __shared__ float Bs[BK][BN+1];
  int bn = blockIdx.x * BN;
  int tid = threadIdx.x;
  int tx = tid & 15, ty = tid >> 4;
  int lr = tid >> 2;
  int lk = (tid & 3) * 4;
  int lrow_ld = mbase + lr;
  int gpos_ld = obase + (lrow_ld < cnt ? lrow_ld : 0);
  gpos_ld = gpos_ld < 0 ? 0 : (gpos_ld > BTOK-1 ? BTOK-1 : gpos_ld);
  int arow = (mode == 0) ? rowmap[gpos_ld] : gpos_ld;
  arow = arow < 0 ? 0 : (arow > BTOK-1 ? BTOK-1 : arow);  // safety clamp
  const bf16*  Ap = A + (size_t)arow*K + lk;
  const float* Wp = W + (size_t)(bn + lr)*K + lk;
  float acc[4][4] = {};
  for (int k0 = 0; k0 < K; k0 += BK){
    #pragma unroll
    for (int j = 0; j < 4; ++j){
      As[lk+j][lr] = b2f(Ap[k0 + j]);
      Bs[lk+j][lr] = Wp[k0 + j];
    }
    __syncthreads();
    #pragma unroll
    for (int kk = 0; kk < BK; ++kk){
      float av[4], bv[4];
      #pragma unroll
      for (int i = 0; i < 4; ++i) av[i] = As[kk][ty*4 + i];
      #pragma unroll
      for (int j = 0; j < 4; ++j) bv[j] = Bs[kk][tx*4 + j];
      #pragma unroll
      for (int i = 0; i < 4; ++i)
        #pragma unroll
        for (int j = 0; j < 4; ++j) acc[i][j] = fmaf(av[i], bv[j], acc[i][j]);
    }
    __syncthreads();
  }
  #pragma unroll
  for (int i = 0; i < 4; ++i){
    int lrow = mbase + ty*4 + i;
    if (lrow >= cnt) continue;
    int gpos = obase + lrow;
    int orow = (mode == 0) ? gpos : rowmap[gpos];
    orow = orow < 0 ? 0 : (orow > BTOK-1 ? BTOK-1 : orow);
    #pragma unroll
    for (int j = 0; j < 4; ++j){
      int col = bn + tx*4 + j;
      size_t oi = (size_t)orow*N + col;
      if (mode == 0){
        float v = acc[i][j] > 0.f ? acc[i][j] : 0.f;
        Obf[oi] = f2b(v*v);
      } else {
        Of32[oi] += acc[i][j];   // unique (row,col) writer across experts
      }
    }
  }
}

// ================= chunk-parallel WKV =================
// state recurrence: s_{t+1}[n][m] = w_t[n]*s_t[n][m] + k_t[n]*v_t[m]  (per (b,h))
// decomposed into per-chunk B_c (recurrence from 0) and A_c (decay product),
// sequential cross-chunk combine, then intra-chunk output replay.

// precompute w = exp(-exp(td + bias)) elementwise
__global__ void k_wprep(const float* __restrict__ td, const float* __restrict__ bias,
                        float* __restrict__ wbuf, int n){
  int i = blockIdx.x*256 + threadIdx.x;
  if (i >= n) return;
  wbuf[i] = expf(-expf(td[i] + bias[i & (AA-1)]));
}

// pass 1: per (stream=b*16+h, chunk): B_c[n][m], A_c[n]
__global__ __launch_bounds__(64) void k_wkv_chunk(
    const float* __restrict__ kb, const float* __restrict__ vb,
    const float* __restrict__ wb, float* __restrict__ Bc, float* __restrict__ Ac){
  int blk = blockIdx.x;
  int stream = blk >> 4, c = blk & (NCHUNK-1);
  int b = stream >> 4, hh = stream & 15;
  int lane = threadIdx.x;          // m column (and n for the A-product)
  __shared__ float ks[64], ws[64];
  float s[64];
  #pragma unroll
  for (int n = 0; n < 64; ++n) s[n] = 0.f;
  float prod = 1.f;
  int t0 = c * CHUNK;
  for (int tt = 0; tt < CHUNK; ++tt){
    size_t idx = ((size_t)(b*1024 + t0 + tt))*AA + hh*64 + lane;
    float kt = kb[idx], vt = vb[idx], wt = wb[idx];
    __syncthreads();
    ks[lane] = kt; ws[lane] = wt;
    __syncthreads();
    prod *= wt;                     // lane acts as n here
    #pragma unroll
    for (int n = 0; n < 64; ++n)
      s[n] = fmaf(ws[n], s[n], ks[n]*vt);
  }
  float* Bp = Bc + ((size_t)stream*NCHUNK + c)*4096;
  #pragma unroll
  for (int n = 0; n < 64; ++n) Bp[n*64 + lane] = s[n];
  Ac[((size_t)stream*NCHUNK + c)*64 + lane] = prod;
}

// pass 2: sequential over chunks; overwrite Bc slots with chunk-INITIAL states
__global__ __launch_bounds__(64) void k_wkv_combine(
    float* __restrict__ Bc, const float* __restrict__ Ac){
  int stream = blockIdx.x;
  int lane = threadIdx.x;          // m
  __shared__ float as[64];
  float S[64];
  #pragma unroll
  for (int n = 0; n < 64; ++n) S[n] = 0.f;
  for (int c = 0; c < NCHUNK; ++c){
    __syncthreads();
    as[lane] = Ac[((size_t)stream*NCHUNK + c)*64 + lane];
    __syncthreads();
    float* Bp = Bc + ((size_t)stream*NCHUNK + c)*4096;
    #pragma unroll
    for (int n = 0; n < 64; ++n){
      float bcv = Bp[n*64 + lane];
      Bp[n*64 + lane] = S[n];                 // store chunk-initial state
      S[n] = fmaf(as[n], S[n], bcv);
    }
  }
}

// pass 3: replay each chunk from its initial state, emit outputs
__global__ __launch_bounds__(64) void k_wkv_out(
    const float* __restrict__ rb, const float* __restrict__ kb,
    const float* __restrict__ vb, const float* __restrict__ wb,
    const float* __restrict__ u, const float* __restrict__ Sc,
    float* __restrict__ ob){
  int blk = blockIdx.x;
  int stream = blk >> 4, c = blk & (NCHUNK-1);
  int b = stream >> 4, hh = stream & 15;
  int lane = threadIdx.x;          // m
  __shared__ float rs[64], ks[64], ws[64], us[64];
  us[lane] = u[hh*64 + lane];
  const float* Sp = Sc + ((size_t)stream*NCHUNK + c)*4096;
  float s[64];
  #pragma unroll
  for (int n = 0; n < 64; ++n) s[n] = Sp[n*64 + lane];
  int t0 = c * CHUNK;
  for (int tt = 0; tt < CHUNK; ++tt){
    size_t idx = ((size_t)(b*1024 + t0 + tt))*AA + hh*64 + lane;
    float rt = rb[idx], kt = kb[idx], vt = vb[idx], wt = wb[idx];
    __syncthreads();
    rs[lane] = rt; ks[lane] = kt; ws[lane] = wt;
    __syncthreads();
    float o0 = 0.f, o1 = 0.f;
    #pragma unroll
    for (int n = 0; n < 64; n += 2){
      float kv0 = ks[n]*vt;
      o0 = fmaf(rs[n], fmaf(us[n], kv0, s[n]), o0);
      s[n] = fmaf(ws[n], s[n], kv0);
      float kv1 = ks[n+1]*vt;
      o1 = fmaf(rs[n+1], fmaf(us[n+1], kv1, s[n+1]), o1);
      s[n+1] = fmaf(ws[n+1], s[n+1], kv1);
    }
    ob[idx] = o0 + o1;
  }
}

// ---------------- group-norm over heads + silu(g) gate -> ao (f32) ----------------
__global__ __launch_bounds__(256) void k_gnorm_gate(
    const float* __restrict__ ob, const float* __restrict__ gb,
    const float* __restrict__ lg, const float* __restrict__ lb, float* __restrict__ ao){
  int t = blockIdx.x, tid = threadIdx.x;
  int lane = tid & 63, wid = tid >> 6;
  #pragma unroll
  for (int i = 0; i < 4; ++i){
    int head = wid*4 + i;
    int cidx = head*64 + lane;
    size_t idx = (size_t)t*AA + cidx;
    float v = ob[idx];
    float s1 = v, s2 = v*v;
    #pragma unroll
    for (int o = 32; o > 0; o >>= 1){
      s1 += __shfl_xor(s1, o, 64);
      s2 += __shfl_xor(s2, o, 64);
    }
    float m   = s1 * (1.f/64.f);
    float var = s2 * (1.f/64.f) - m*m;
    float nv  = (v - m) * rsqrtf(var + 6.4e-4f) * lg[cidx] + lb[cidx]; // eps=1e-5*64
    float gv  = gb[idx];
    float gate = gv / (1.f + expf(-gv));  // silu
    ao[idx] = nv * gate;
  }
}

// ---------------- ln2 + ffn token-shift mix -> zfr,zfk (bf16 scratch) ----------------
__global__ __launch_bounds__(256) void k_ln2mix(
    const float* __restrict__ x2,
    const float* __restrict__ g2, const float* __restrict__ b2v,
    const float* __restrict__ fmaa_r, const float* __restrict__ fmaa_k,
    bf16* __restrict__ zfr, bf16* __restrict__ zfk){
  __shared__ float red[8];
  int t = blockIdx.x, tid = threadIdx.x;
  int tb = t & 1023;
  float cur[4], prv[4];
  #pragma unroll
  for (int i = 0; i < 4; ++i){
    int c = tid + 256*i;
    cur[i] = x2[(size_t)t*CC + c];
    prv[i] = tb ? x2[(size_t)(t-1)*CC + c] : 0.f;
  }
  float m1 = block_sum256(cur[0]+cur[1]+cur[2]+cur[3], red) * (1.f/CC);
  float vs = 0.f;
  #pragma unroll
  for (int i = 0; i < 4; ++i){ float d = cur[i]-m1; vs += d*d; }
  float inv1 = rsqrtf(block_sum256(vs, red)*(1.f/CC) + 1e-5f);
  float m2 = block_sum256(prv[0]+prv[1]+prv[2]+prv[3], red) * (1.f/CC);
  vs = 0.f;
  #pragma unroll
  for (int i = 0; i < 4; ++i){ float d = prv[i]-m2; vs += d*d; }
  float inv2 = rsqrtf(block_sum256(vs, red)*(1.f/CC) + 1e-5f);
  #pragma unroll
  for (int i = 0; i < 4; ++i){
    int c = tid + 256*i;
    float hc = (cur[i]-m1)*inv1*g2[c] + b2v[c];
    float hp = tb ? ((prv[i]-m2)*inv2*g2[c] + b2v[c]) : 0.f;
    float d = hp - hc;
    zfr[(size_t)t*CC + c] = f2b(hc + d * fmaa_r[c]);
    zfk[(size_t)t*CC + c] = f2b(hc + d * fmaa_k[c]);
  }
}

// ---------------- expert routing ----------------
__global__ __launch_bounds__(256) void k_route(
    const int* __restrict__ ids, int* __restrict__ rowmap,
    int* __restrict__ counts, int* __restrict__ offsets){
  __shared__ int cnt[8], cur[8], off[8];
  int tid = threadIdx.x;
  if (tid < 8){ cnt[tid] = 0; cur[tid] = 0; }
  __syncthreads();
  for (int t = tid; t < BTOK; t += 256){
    int e = (ids[t] * 5099) & 7;
    atomicAdd(&cnt[e], 1);
  }
  __syncthreads();
  if (tid == 0){
    int acc = 0;
    for (int e = 0; e < 8; ++e){ off[e] = acc; offsets[e] = acc; counts[e] = cnt[e]; acc += cnt[e]; }
  }
  __syncthreads();
  for (int t = tid; t < BTOK; t += 256){
    int e = (ids[t] * 5099) & 7;
    int pos = off[e] + atomicAdd(&cur[e], 1);
    rowmap[pos] = t;
  }
}

// ---------------- small elementwise ----------------
__global__ void k_tanh_f(const float* __restrict__ in, float* __restrict__ out, int n){
  int i = blockIdx.x*256 + threadIdx.x;
  if (i >= n) return;
  out[i] = tanhf(in[i]);
}
__global__ void k_transpose_f(const float* __restrict__ in, float* __restrict__ out, int R, int Ccol){
  int idx = blockIdx.x*256 + threadIdx.x;
  if (idx >= R*Ccol) return;
  int r = idx / Ccol, c = idx % Ccol;
  out[c*R + r] = in[idx];
}
__global__ void k_final(const float* __restrict__ x2, const float* __restrict__ rr,
                        const float* __restrict__ val, float* __restrict__ out, int n){
  int i = blockIdx.x*256 + threadIdx.x;
  if (i >= n) return;
  float r = 1.f / (1.f + expf(-rr[i]));
  out[i] = x2[i] + r*val[i];
}

// ---------------- launch ----------------
extern "C" void kernel_launch(void* const* d_in, const int* in_sizes, int n_in,
                              void* d_out, int out_size, void* d_ws, size_t ws_size,
                              hipStream_t stream) {
  const float* hidden  = (const float*)d_in[0];
  const int*   ids     = (const int*)  d_in[1];
  const float* pre_g   = (const float*)d_in[2];
  const float* pre_b   = (const float*)d_in[3];
  const float* ln1_g   = (const float*)d_in[4];
  const float* ln1_b   = (const float*)d_in[5];
  const float* ln2_g   = (const float*)d_in[6];
  const float* ln2_b   = (const float*)d_in[7];
  const float* maa_x   = (const float*)d_in[8];
  const float* maa_w   = (const float*)d_in[9];
  const float* maa_k   = (const float*)d_in[10];
  const float* maa_v   = (const float*)d_in[11];
  const float* maa_r   = (const float*)d_in[12];
  const float* maa_g   = (const float*)d_in[13];
  const float* maa_w1  = (const float*)d_in[14];
  const float* maa_w2  = (const float*)d_in[15];
  const float* att_td  = (const float*)d_in[16];
  const float* td_w1   = (const float*)d_in[17];
  const float* td_w2   = (const float*)d_in[18];
  const float* att_u   = (const float*)d_in[19];
  const float* att_wr  = (const float*)d_in[20];
  const float* att_wk  = (const float*)d_in[21];
  const float* att_wv  = (const float*)d_in[22];
  const float* att_wg  = (const float*)d_in[23];
  const float* att_wo  = (const float*)d_in[24];
  const float* lnx_g   = (const float*)d_in[25];
  const float* lnx_b   = (const float*)d_in[26];
  const float* fmaa_k  = (const float*)d_in[27];
  const float* fmaa_r  = (const float*)d_in[28];
  const float* ffn_wr  = (const float*)d_in[29];
  const float* sh_wk   = (const float*)d_in[30];
  const float* sh_wv   = (const float*)d_in[31];
  const float* ex_wk   = (const float*)d_in[32];
  const float* ex_wv   = (const float*)d_in[33];
  (void)ws_size; (void)n_in; (void)in_sizes; (void)out_size;

  // ---- workspace layout, lifetime-aliased (total ≈ 69.6 MB) ----
  char* base = (char*)d_ws;
  const size_t F = (size_t)BTOK * CC * 4;       // 8 MiB plane
  float* x      = (float*)(base + 0*F);         // S1 -> S12; x2 aliases x
  float* x2     = x;
  float* h      = (float*)(base + 1*F);         // S1 -> S2
  float* rbuf   = h;                            // S3 -> S5
  float* kbuf   = (float*)(base + 2*F);         // S3 -> S5
  float* vbuf   = (float*)(base + 3*F);         // S3 -> S5
  bf16*  hk2    = (bf16*)(base + 2*F);          // S10 -> S11 (over kbuf+vbuf)
  float* gbuf   = (float*)(base + 4*F);         // S3 -> S6
  float* val    = gbuf;                         // S10 -> S12
  float* tdbuf  = (float*)(base + 5*F);         // S4 -> S5a(wprep)
  float* wkvout = tdbuf;                        // S5c writes (tdbuf dead) -> S6
  float* recraw = tdbuf;                        // S9 -> S12
  bf16*  zw     = (bf16*)(base + 6*F);          // z region: [48,68) MB
  bf16*  zk     = zw + (size_t)BTOK*CC;
  bf16*  zv     = zk + (size_t)BTOK*CC;
  bf16*  zr     = zv + (size_t)BTOK*CC;
  bf16*  zg     = zr + (size_t)BTOK*CC;
  float* wbuf   = (float*)(base + 6*F);         // WKV decay, 8 MB over zw+zk (dead after S4a/S3)
  float* chunkS = (float*)(base + 7*F);         // B_c/S_c: 32*16*4096*4 = 8 MB over zv+zr
  float* ao     = (float*)(base + 6*F);         // S6 -> S7 (wbuf dead after S5c)
  bf16*  zfr    = zv;                           // S8 -> S9 (chunkS dead after S5c)
  bf16*  zfk    = zr;                           // S8 -> S11
  char*  misc   = base + 6*F + (size_t)5*BTOK*CC*2;   // 68 MB
  float* tmp64  = (float*)misc;                               // 512 KB; Ac aliases (dead after S4)
  float* Ac     = tmp64;
  float* tanh64 = (float*)(misc + (size_t)BTOK*64*4);         // 512 KB
  float* tdw1T  = (float*)(misc + (size_t)BTOK*64*8);         // 256 KB
  float* tdw2T  = tdw1T + (size_t)64*CC;                      // 256 KB
  int*   rowmap = (int*)(tdw2T + (size_t)AA*64);              // 8 KB
  int*   counts = rowmap + BTOK;
  int*   offsets= counts + 64;

  // 1. pre_ln + ln1
  k_ln_pre<<<BTOK, 256, 0, stream>>>(hidden, pre_g, pre_b, ln1_g, ln1_b, x, h);
  // 2. attention maa mix -> z_{w,k,v,r,g}
  k_mix_att<<<BTOK, 256, 0, stream>>>(h, maa_x, maa_w1, maa_w2,
                                      maa_w, maa_k, maa_v, maa_r, maa_g,
                                      zw, zk, zv, zr, zg);
  // 3. r,k,v,g projections
  dim3 g1024(CC/BN, BTOK/BM);
  k_gemm<bf16><<<g1024, 256, 0, stream>>>(zr, att_wr, rbuf, nullptr, BTOK, AA, CC, nullptr, 0);
  k_gemm<bf16><<<g1024, 256, 0, stream>>>(zk, att_wk, kbuf, nullptr, BTOK, AA, CC, nullptr, 0);
  k_gemm<bf16><<<g1024, 256, 0, stream>>>(zv, att_wv, vbuf, nullptr, BTOK, AA, CC, nullptr, 0);
  k_gemm<bf16><<<g1024, 256, 0, stream>>>(zg, att_wg, gbuf, nullptr, BTOK, AA, CC, nullptr, 0);
  // 4. td path (tmp64/tanh64 dead after this step)
  k_transpose_f<<<(CC*64 + 255)/256, 256, 0, stream>>>(td_w1, tdw1T, CC, 64);
  k_transpose_f<<<(64*AA + 255)/256, 256, 0, stream>>>(td_w2, tdw2T, 64, AA);
  k_gemm<bf16><<<dim3(1, BTOK/BM), 256, 0, stream>>>(zw, tdw1T, tmp64, nullptr, BTOK, 64, CC, nullptr, 0);
  k_tanh_f<<<(BTOK*64 + 255)/256, 256, 0, stream>>>(tmp64, tanh64, BTOK*64);
  k_gemm<float><<<dim3(AA/BN, BTOK/BM), 256, 0, stream>>>(tanh64, tdw2T, tdbuf, nullptr, BTOK, AA, 64, nullptr, 0);
  // 5. chunk-parallel WKV
  k_wprep<<<(BTOK*AA + 255)/256, 256, 0, stream>>>(tdbuf, att_td, wbuf, BTOK*AA);
  k_wkv_chunk<<<32*NCHUNK, 64, 0, stream>>>(kbuf, vbuf, wbuf, chunkS, Ac);
  k_wkv_combine<<<32, 64, 0, stream>>>(chunkS, Ac);
  k_wkv_out<<<32*NCHUNK, 64, 0, stream>>>(rbuf, kbuf, vbuf, wbuf, att_u, chunkS, wkvout);
  // 6. group-norm + silu gate -> ao
  k_gnorm_gate<<<BTOK, 256, 0, stream>>>(wkvout, gbuf, lnx_g, lnx_b, ao);
  // 7. output proj + residual -> x2 (aliases x; element-wise read-then-write)
  k_gemm<float><<<g1024, 256, 0, stream>>>(ao, att_wo, x2, nullptr, BTOK, CC, AA, x, 0);
  // 8. ln2 + ffn mix
  k_ln2mix<<<BTOK, 256, 0, stream>>>(x2, ln2_g, ln2_b, fmaa_r, fmaa_k, zfr, zfk);
  // 9. receptance
  k_gemm<bf16><<<g1024, 256, 0, stream>>>(zfr, ffn_wr, recraw, nullptr, BTOK, CC, CC, nullptr, 0);
  // 10. shared expert (relu^2 fused into key GEMM epilogue)
  k_gemm<bf16><<<dim3(IDIM/BN, BTOK/BM), 256, 0, stream>>>(zfk, sh_wk, nullptr, hk2, BTOK, IDIM, CC, nullptr, 1);
  k_gemm<bf16><<<g1024, 256, 0, stream>>>(hk2, sh_wv, val, nullptr, BTOK, CC, IDIM, nullptr, 0);
  // 11. routed experts
  k_route<<<1, 256, 0, stream>>>(ids, rowmap, counts, offsets);
  k_gemm_moe<<<dim3(IDIM/BN, BTOK/BM, NEXP), 256, 0, stream>>>(
      zfk, ex_wk, (size_t)IDIM*CC, nullptr, hk2, IDIM, CC, rowmap, counts, offsets, 0);
  k_gemm_moe<<<dim3(CC/BN, BTOK/BM, NEXP), 256, 0, stream>>>(
      hk2, ex_wv, (size_t)CC*IDIM, val, nullptr, CC, IDIM, rowmap, counts, offsets, 1);
  // 12. final combine -> f32 out
  k_final<<<(BTOK*CC + 255)/256, 256, 0, stream>>>(x2, recraw, val, (float*)d_out, BTOK*CC);
}